// Round 4
// baseline (85.976 us; speedup 1.0000x reference)
//
#include <hip/hip_runtime.h>
#include <hip/hip_bf16.h>
#include <math.h>

#define TT 512
#define CC 1024
#define NH 16
#define NKV 8
#define HD 64
static constexpr float EPS_ = 1e-6f;

typedef short bf16x8 __attribute__((ext_vector_type(8)));
typedef float f32x4 __attribute__((ext_vector_type(4)));

__device__ __forceinline__ ushort f2bf(float f) {
  union { __hip_bfloat16 h; ushort u; } cv;
  cv.h = __float2bfloat16(f);
  return cv.u;
}

// ---------------------------------------------------------------------------
// prep: x -> bf16 (same layout); Wq/Wk/Wv/Wo -> transposed bf16 Wt[n][k]
// ---------------------------------------------------------------------------
__global__ __launch_bounds__(256) void prep_kernel(
    const float* __restrict__ x,
    const float* __restrict__ Wq, const float* __restrict__ Wk,
    const float* __restrict__ Wv, const float* __restrict__ Wo,
    ushort* __restrict__ xb, ushort* __restrict__ Wtq, ushort* __restrict__ Wtk,
    ushort* __restrict__ Wtv, ushort* __restrict__ Wto)
{
  int b = blockIdx.x;
  if (b < 256) {
    int base = b * 2048 + threadIdx.x * 8;
    float4 f0 = *reinterpret_cast<const float4*>(&x[base]);
    float4 f1 = *reinterpret_cast<const float4*>(&x[base + 4]);
    union { ushort u[8]; uint4 v; } pk;
    pk.u[0] = f2bf(f0.x); pk.u[1] = f2bf(f0.y); pk.u[2] = f2bf(f0.z); pk.u[3] = f2bf(f0.w);
    pk.u[4] = f2bf(f1.x); pk.u[5] = f2bf(f1.y); pk.u[6] = f2bf(f1.z); pk.u[7] = f2bf(f1.w);
    *reinterpret_cast<uint4*>(&xb[base]) = pk.v;
    return;
  }
  b -= 256;
  const float* W; ushort* Wt; int ldW, tr, tc;
  if (b < 256)      { W = Wq; Wt = Wtq; ldW = 1024; tr = b >> 4;       tc = b & 15; }
  else if (b < 384) { int q = b - 256; W = Wk; Wt = Wtk; ldW = 512; tr = q >> 3; tc = q & 7; }
  else if (b < 512) { int q = b - 384; W = Wv; Wt = Wtv; ldW = 512; tr = q >> 3; tc = q & 7; }
  else              { int q = b - 512; W = Wo; Wt = Wto; ldW = 1024; tr = q >> 4; tc = q & 15; }
  const int k0 = tr * 64, n0 = tc * 64;
  __shared__ float ft[64][65];
  const int t = threadIdx.x;
#pragma unroll
  for (int it = 0; it < 4; ++it) {
    int q = t + it * 256;
    int r = q >> 4, c4 = q & 15;
    float4 f = *reinterpret_cast<const float4*>(&W[(k0 + r) * ldW + n0 + c4 * 4]);
    ft[r][c4 * 4 + 0] = f.x; ft[r][c4 * 4 + 1] = f.y;
    ft[r][c4 * 4 + 2] = f.z; ft[r][c4 * 4 + 3] = f.w;
  }
  __syncthreads();
#pragma unroll
  for (int it = 0; it < 2; ++it) {
    int q = t + it * 256;
    int n = q >> 3, kc = q & 7;
    union { ushort u[8]; uint4 v; } pk;
#pragma unroll
    for (int j = 0; j < 8; ++j) pk.u[j] = f2bf(ft[kc * 8 + j][n]);
    *reinterpret_cast<uint4*>(&Wt[(n0 + n) * 1024 + k0 + kc * 8]) = pk.v;
  }
}

// ---------------------------------------------------------------------------
// bf16 MFMA GEMM: C[64x64 tile] = A[M][1024] @ Bt[N][1024]^T, fp32 out.
// ---------------------------------------------------------------------------
__device__ __forceinline__ void mfma_gemm64(
    const ushort* __restrict__ A, const ushort* __restrict__ Bt,
    float* __restrict__ C, int ldC, int row0, int col0)
{
  __shared__ ushort At[64][72];
  __shared__ ushort Bs[64][72];
  const int tid = threadIdx.x;
  const int lane = tid & 63, w = tid >> 6;
  const int m0 = (w & 1) * 32, n0 = (w >> 1) * 32;
  const int lr = lane & 15, lk = (lane >> 4) * 8;
  f32x4 acc[2][2] = {};
  const int sr = tid >> 2;
  const int sc = (tid & 3) * 16;
  const ushort* Ap = &A[(row0 + sr) * 1024 + sc];
  const ushort* Bp = &Bt[(col0 + sr) * 1024 + sc];

  for (int k0 = 0; k0 < 1024; k0 += 64) {
    __syncthreads();
    uint4 a0 = *reinterpret_cast<const uint4*>(Ap + k0);
    uint4 a1 = *reinterpret_cast<const uint4*>(Ap + k0 + 8);
    uint4 b0 = *reinterpret_cast<const uint4*>(Bp + k0);
    uint4 b1 = *reinterpret_cast<const uint4*>(Bp + k0 + 8);
    *reinterpret_cast<uint4*>(&At[sr][sc]) = a0;
    *reinterpret_cast<uint4*>(&At[sr][sc + 8]) = a1;
    *reinterpret_cast<uint4*>(&Bs[sr][sc]) = b0;
    *reinterpret_cast<uint4*>(&Bs[sr][sc + 8]) = b1;
    __syncthreads();
#pragma unroll
    for (int kk = 0; kk < 2; ++kk) {
      bf16x8 af[2], bg[2];
      af[0] = *reinterpret_cast<const bf16x8*>(&At[m0 + lr][kk * 32 + lk]);
      af[1] = *reinterpret_cast<const bf16x8*>(&At[m0 + 16 + lr][kk * 32 + lk]);
      bg[0] = *reinterpret_cast<const bf16x8*>(&Bs[n0 + lr][kk * 32 + lk]);
      bg[1] = *reinterpret_cast<const bf16x8*>(&Bs[n0 + 16 + lr][kk * 32 + lk]);
#pragma unroll
      for (int mi = 0; mi < 2; ++mi)
#pragma unroll
        for (int ni = 0; ni < 2; ++ni)
          acc[mi][ni] = __builtin_amdgcn_mfma_f32_16x16x32_bf16(af[mi], bg[ni], acc[mi][ni], 0, 0, 0);
    }
  }
  const int crow = (lane >> 4) * 4, ccol = lane & 15;
#pragma unroll
  for (int mi = 0; mi < 2; ++mi)
#pragma unroll
    for (int ni = 0; ni < 2; ++ni) {
      int rb = row0 + m0 + mi * 16 + crow;
      int cc = col0 + n0 + ni * 16 + ccol;
#pragma unroll
      for (int r = 0; r < 4; ++r)
        C[(rb + r) * ldC + cc] = acc[mi][ni][r];
    }
}

__global__ __launch_bounds__(256) void qkv_mfma_kernel(
    const ushort* __restrict__ xb,
    const ushort* __restrict__ Wtq, const ushort* __restrict__ Wtk, const ushort* __restrict__ Wtv,
    float* __restrict__ qb, float* __restrict__ kb, float* __restrict__ vb)
{
  int bx = blockIdx.x, by = blockIdx.y;
  if (bx < 16)      mfma_gemm64(xb, Wtq, qb, 1024, by * 64, bx * 64);
  else if (bx < 24) mfma_gemm64(xb, Wtk, kb, 512, by * 64, (bx - 16) * 64);
  else              mfma_gemm64(xb, Wtv, vb, 512, by * 64, (bx - 24) * 64);
}

__global__ __launch_bounds__(256) void out_mfma_kernel(
    const ushort* __restrict__ yb, const ushort* __restrict__ Wto, float* __restrict__ out)
{
  mfma_gemm64(yb, Wto, out, 1024, blockIdx.y * 64, blockIdx.x * 64);
}

// ---------------------------------------------------------------------------
// RoPE + RMS-norm, in place (fp32).
// ---------------------------------------------------------------------------
__global__ __launch_bounds__(256) void rope_rms_kernel(
    float* __restrict__ qb, float* __restrict__ kb,
    const float* __restrict__ cosb, const float* __restrict__ sinb)
{
  int rid = blockIdx.x * 4 + (threadIdx.x >> 6);
  int lane = threadIdx.x & 63;
  float* p; int t;
  if (rid < TT * NH) { t = rid >> 4; p = qb + t * 1024 + (rid & 15) * 64; }
  else { int r2 = rid - TT * NH; t = r2 >> 3; p = kb + t * 512 + (r2 & 7) * 64; }

  float v = p[lane];
  float part = __shfl_xor(v, 32);
  int f = lane & 31;
  float c = cosb[t * 32 + f], s = sinb[t * 32 + f];
  float o = (lane < 32) ? (v * c - part * s) : (part * s + v * c);
  float ss = o * o;
#pragma unroll
  for (int off = 32; off; off >>= 1) ss += __shfl_xor(ss, off);
  float r = rsqrtf(ss * (1.0f / 64.0f) + EPS_);
  p[lane] = o * r;
}

// ---------------------------------------------------------------------------
// Tropical causal attention, v3.
// Block = (kv-head g, 8-row q-chunk). 256 thr = 4 waves; waves 0-1 -> head 2g,
// waves 2-3 -> head 2g+1; each wave owns 4 q-rows. K/V staged once per block
// (serves both heads). Deferred softmax: no per-tile reduces (scores are
// bounded, |s| <~ 16, exp safe in fp32); per-lane lsum, one reduce at end.
// Async staging: next tile global->regs overlaps current tile compute.
// ---------------------------------------------------------------------------
__global__ __launch_bounds__(256) void attn_kernel(
    const float* __restrict__ qb, const float* __restrict__ kb,
    const float* __restrict__ vb, ushort* __restrict__ yb)
{
  __shared__ float kS[64][76];
  __shared__ float vS[64][76];
  __shared__ __align__(16) float qS[16][64];
  __shared__ __align__(16) float pS[4][4][64];

  const int tid = threadIdx.x;
  const int w = tid >> 6, lane = tid & 63;
  const int bx = blockIdx.x;
  const int g = bx & 7;
  const int qc = 63 - (bx >> 3);        // heavy chunks first
  const int i0 = qc * 8;
  const int nt = (i0 >> 6) + 1;
  const int h = 2 * g + (w >> 1);
  const int rbase = 4 * (w & 1);        // row offset within this head's 8 rows
  const int qrow = (w >> 1) * 8 + rbase;

  // stage the 16 q rows (2 heads x 8 rows)
  {
    int r16 = tid >> 4, c4 = tid & 15;
    int hh = r16 >> 3, r = r16 & 7;
    float4 qv = *reinterpret_cast<const float4*>(
        &qb[(i0 + r) * 1024 + (2 * g + hh) * 64 + c4 * 4]);
    *reinterpret_cast<float4*>(&qS[r16][c4 * 4]) = qv;
  }

  // async staging registers: 64B of K and V per thread
  const int sr = tid >> 2;              // row 0..63
  const int sc = (tid & 3) * 16;        // col base (floats)
  float4 ka[4], va[4];
  {
    const float* kp = &kb[sr * 512 + g * 64 + sc];
    const float* vp = &vb[sr * 512 + g * 64 + sc];
#pragma unroll
    for (int u = 0; u < 4; ++u) {
      ka[u] = *reinterpret_cast<const float4*>(kp + u * 4);
      va[u] = *reinterpret_cast<const float4*>(vp + u * 4);
    }
  }

  float acc[4]  = {0.f, 0.f, 0.f, 0.f};
  float lsum[4] = {0.f, 0.f, 0.f, 0.f};

  for (int jt = 0; jt < nt; ++jt) {
    __syncthreads();                    // prev compute done; LDS reusable
#pragma unroll
    for (int u = 0; u < 4; ++u) {
      *reinterpret_cast<float4*>(&kS[sr][sc + u * 4]) = ka[u];
      *reinterpret_cast<float4*>(&vS[sr][sc + u * 4]) = va[u];
    }
    __syncthreads();                    // LDS ready
    if (jt + 1 < nt) {                  // prefetch next tile (overlaps compute)
      const float* kp = &kb[((jt + 1) * 64 + sr) * 512 + g * 64 + sc];
      const float* vp = &vb[((jt + 1) * 64 + sr) * 512 + g * 64 + sc];
#pragma unroll
      for (int u = 0; u < 4; ++u) {
        ka[u] = *reinterpret_cast<const float4*>(kp + u * 4);
        va[u] = *reinterpret_cast<const float4*>(vp + u * 4);
      }
    }

    // K row (j = j0+lane) into registers
    float kreg[64];
#pragma unroll
    for (int d4 = 0; d4 < 16; ++d4)
      *reinterpret_cast<float4*>(&kreg[d4 * 4]) =
          *reinterpret_cast<const float4*>(&kS[lane][d4 * 4]);
    // V column (d = lane) into registers
    float vreg[64];
#pragma unroll
    for (int j = 0; j < 64; ++j) vreg[j] = vS[j][lane];

    const int j0 = jt * 64;
    const bool lastT = (jt == nt - 1);

#pragma unroll
    for (int q = 0; q < 4; ++q) {
      const int i = i0 + rbase + q;
      const float4* q4 = reinterpret_cast<const float4*>(qS[qrow + q]);
      float s0 = -INFINITY, s1 = -INFINITY;
#pragma unroll
      for (int d4 = 0; d4 < 16; ++d4) {
        float4 qv = q4[d4];
        s0 = fmaxf(fmaxf(s0, qv.x + kreg[d4 * 4 + 0]), qv.y + kreg[d4 * 4 + 1]);
        s1 = fmaxf(fmaxf(s1, qv.z + kreg[d4 * 4 + 2]), qv.w + kreg[d4 * 4 + 3]);
      }
      float s = fmaxf(s0, s1);
      if (lastT && (j0 + lane > i)) s = -INFINITY;
      float pp = __expf(s);             // bounded: q,k RMS-normed
      lsum[q] += pp;
      pS[w][q][lane] = pp;
    }

    // PV: register-resident V column, broadcast P reads (same-wave LDS RAW)
#pragma unroll
    for (int q = 0; q < 4; ++q) {
      const float4* p4 = reinterpret_cast<const float4*>(pS[w][q]);
      float a = acc[q];
#pragma unroll
      for (int j4 = 0; j4 < 16; ++j4) {
        float4 pv = p4[j4];
        a = fmaf(pv.x, vreg[j4 * 4 + 0], a);
        a = fmaf(pv.y, vreg[j4 * 4 + 1], a);
        a = fmaf(pv.z, vreg[j4 * 4 + 2], a);
        a = fmaf(pv.w, vreg[j4 * 4 + 3], a);
      }
      acc[q] = a;
    }
  }

  // epilogue: one lsum reduce per q-row, write y as bf16
#pragma unroll
  for (int q = 0; q < 4; ++q) {
    float l = lsum[q];
#pragma unroll
    for (int off = 32; off; off >>= 1) l += __shfl_xor(l, off);
    int i = i0 + rbase + q;
    yb[i * 1024 + h * 64 + lane] = f2bf(acc[q] / l);
  }
}

// ---------------------------------------------------------------------------
extern "C" void kernel_launch(void* const* d_in, const int* in_sizes, int n_in,
                              void* d_out, int out_size, void* d_ws, size_t ws_size,
                              hipStream_t stream) {
  const float* x    = (const float*)d_in[0];
  const float* cosb = (const float*)d_in[1];
  const float* sinb = (const float*)d_in[2];
  const float* Wq   = (const float*)d_in[3];
  const float* Wk   = (const float*)d_in[4];
  const float* Wv   = (const float*)d_in[5];
  const float* Wo   = (const float*)d_in[6];
  float* out = (float*)d_out;

  float* wsf = (float*)d_ws;
  float* qbuf = wsf;                      // 512x1024 f32
  float* kbuf = qbuf + TT * CC;           // 512x512  f32
  float* vbuf = kbuf + TT * 512;          // 512x512  f32
  ushort* wsu = (ushort*)(vbuf + TT * 512);
  ushort* xb  = wsu;                      // 512x1024 bf16
  ushort* yb  = xb + TT * CC;             // 512x1024 bf16
  ushort* Wtq = yb + TT * CC;             // 1024x1024 bf16
  ushort* Wtk = Wtq + CC * CC;            // 512x1024 bf16
  ushort* Wtv = Wtk + 512 * CC;           // 512x1024 bf16
  ushort* Wto = Wtv + 512 * CC;           // 1024x1024 bf16

  prep_kernel<<<dim3(1024), 256, 0, stream>>>(x, Wq, Wk, Wv, Wo, xb, Wtq, Wtk, Wtv, Wto);
  qkv_mfma_kernel<<<dim3(32, 8), 256, 0, stream>>>(xb, Wtq, Wtk, Wtv, qbuf, kbuf, vbuf);
  rope_rms_kernel<<<dim3((TT * NH + TT * NKV) / 4), 256, 0, stream>>>(qbuf, kbuf, cosb, sinb);
  attn_kernel<<<dim3(512), 256, 0, stream>>>(qbuf, kbuf, vbuf, yb);
  out_mfma_kernel<<<dim3(16, 8), 256, 0, stream>>>(yb, Wto, out);
}